// Round 14
// baseline (512.074 us; speedup 1.0000x reference)
//
#include <hip/hip_runtime.h>
#include <math.h>

typedef unsigned short u16;
typedef unsigned int u32;
typedef __bf16 bf16;
typedef bf16 bf16x8 __attribute__((ext_vector_type(8)));
typedef float f32x4 __attribute__((ext_vector_type(4)));

#define DEV __device__ __forceinline__
#define MFMA(a, b, c) __builtin_amdgcn_mfma_f32_16x16x32_bf16(a, b, c, 0, 0, 0)

DEV u16 f2b(float f) {
  unsigned u = __builtin_bit_cast(unsigned, f);
  u += 0x7fffu + ((u >> 16) & 1u);
  return (u16)(u >> 16);
}
DEV float b2f(u16 h) {
  unsigned u = ((unsigned)h) << 16;
  return __builtin_bit_cast(float, u);
}
// gelu(x) ~= x * sigmoid(1.5957691x + 0.0713548x^3)  (tanh-form, |err|<=0.003)
DEV float gelu_f(float x) {
  float e = __expf(x * (-1.5957691216f - 0.07135481283f * x * x));
  return x / (1.0f + e);
}

DEV void gl2lds16(const void* g, void* l) {
  __builtin_amdgcn_global_load_lds(
      (const __attribute__((address_space(1))) unsigned int*)g,
      (__attribute__((address_space(3))) unsigned int*)l, 16, 0, 0);
}

// ---------------- fused 6-matrix transpose + fp32->bf16 ----------------
struct TDesc { const float* src; u16* dst; int R, C, t0, tx; };
struct T6 { TDesc d[6]; };

__global__ void k_transpose6(T6 td) {
  __shared__ float tile[32][33];
  const int id = blockIdx.x;
  TDesc d = td.d[0];
#pragma unroll
  for (int k = 1; k < 6; ++k)
    if (id >= td.d[k].t0) d = td.d[k];
  const int local = id - d.t0;
  const int c0 = (local % d.tx) * 32, r0 = (local / d.tx) * 32;
  const int tx = threadIdx.x, ty = threadIdx.y;  // 32 x 8
#pragma unroll
  for (int i = 0; i < 32; i += 8)
    tile[ty + i][tx] = d.src[(long)(r0 + ty + i) * d.C + c0 + tx];
  __syncthreads();
#pragma unroll
  for (int i = 0; i < 32; i += 8)
    d.dst[(long)(c0 + ty + i) * d.R + r0 + tx] = f2b(tile[tx][ty + i]);
}

// ---------------- FiLM ss = cond @ fw + fb, split-K, both films ----------------
__global__ __launch_bounds__(256) void k_film_part(const float* __restrict__ cond,
                                                   const float* __restrict__ f1w,
                                                   const float* __restrict__ f2w,
                                                   float* __restrict__ part) {
  const int j = blockIdx.x * 256 + threadIdx.x;  // 0..2047
  const int b = blockIdx.y;                      // 0..3
  const int z = blockIdx.z;                      // 0..15
  const int kz = z & 7;
  const float* fw = (z < 8) ? f1w : f2w;
  const float* cp = cond + b * 1024 + kz * 128;
  const float* wp = fw + (long)kz * 128 * 2048 + j;
  float acc = 0.0f;
#pragma unroll 4
  for (int d = 0; d < 128; ++d) acc = fmaf(cp[d], wp[(long)d * 2048], acc);
  part[((z * 4 + b) << 11) + j] = acc;
}
__global__ __launch_bounds__(256) void k_film_comb(const float* __restrict__ part,
                                                   const float* __restrict__ f1b,
                                                   const float* __restrict__ f2b_,
                                                   float* __restrict__ ss) {
  const int j = blockIdx.x * 256 + threadIdx.x;
  const int b = blockIdx.y & 3, f = blockIdx.y >> 2;
  float a = (f ? f2b_ : f1b)[j];
#pragma unroll
  for (int kz = 0; kz < 8; ++kz) a += part[(((f * 8 + kz) * 4 + b) << 11) + j];
  ss[((f * 4 + b) << 11) + j] = a;
}

// ---------------- fused RMSNorm + FiLM -> bf16 (fp32 or bf16 input) ----------------
template <typename InT>
__global__ __launch_bounds__(256) void k_rmsfilm(const InT* __restrict__ x,
                                                 const float* __restrict__ nw,
                                                 const float* __restrict__ ss,
                                                 u16* __restrict__ h) {
  const int row = blockIdx.x;
  const int b = row >> 11;
  const int t = threadIdx.x;
  float4 v;
  if constexpr (sizeof(InT) == 4) {
    v = ((const float4*)(x + (long)row * 1024))[t];
  } else {
    ushort4 u = ((const ushort4*)(x + (long)row * 1024))[t];
    v = make_float4(b2f(u.x), b2f(u.y), b2f(u.z), b2f(u.w));
  }
  float s = v.x * v.x + v.y * v.y + v.z * v.z + v.w * v.w;
#pragma unroll
  for (int off = 32; off; off >>= 1) s += __shfl_xor(s, off);
  __shared__ float red[4];
  const int wv = t >> 6, lane = t & 63;
  if (lane == 0) red[wv] = s;
  __syncthreads();
  const float tot = red[0] + red[1] + red[2] + red[3];
  const float rn = rsqrtf(tot * (1.0f / 1024.0f) + 1e-6f);
  const float4 w4 = ((const float4*)nw)[t];
  const float4 sc = ((const float4*)(ss + b * 2048))[t];
  const float4 sh = ((const float4*)(ss + b * 2048 + 1024))[t];
  ushort4 o;
  o.x = f2b(v.x * rn * w4.x * (1.0f + sc.x) + sh.x);
  o.y = f2b(v.y * rn * w4.y * (1.0f + sc.y) + sh.y);
  o.z = f2b(v.z * rn * w4.z * (1.0f + sc.z) + sh.z);
  o.w = f2b(v.w * rn * w4.w * (1.0f + sc.w) + sh.w);
  ((ushort4*)(h + (long)row * 1024))[t] = o;
}

// ---------------- rowsum combine: inv[r] = 1 / sum_b part[b][r] ----------------
__global__ __launch_bounds__(256) void k_rowsuminv(const float* __restrict__ part,
                                                   float* __restrict__ inv) {
  const int id = blockIdx.x * 256 + threadIdx.x;  // 0..8191
  float s = 0.0f;
#pragma unroll
  for (int b = 0; b < 16; ++b) s += part[b * 8192 + id];
  inv[id] = 1.0f / s;
}

// ---------------- m97-form bf16 MFMA GEMM, 128xBN tile, BK=64 ----------------
// C = A[M,K] @ Bt[N,K]^T. 4 waves (2x2), single-buffered LDS, 2 syncs per
// K-step. LDS rows 128B (BK=64); XOR-swizzle slot^=(row&7) on the pre-swizzled
// global source (linear global_load_lds dest) and on ds_read.
// MINB: min blocks/CU hint — LDS admits 5 (BN=128, 32KB) / 6 (BN=64, 24KB);
// VGPR ~60 fits the 8-wave/SIMD budget, so the hint is free occupancy.
// Block mapping: 8x8 supertile traversal per XCD (4MB L2 window).
// Epilogue: LDS-bounce -> 16B vectorized stores; V-columns direct to Vt.
enum { EB = 1, ES = 2, EG = 4, ER = 8, EQKV = 16, ERB = 32, EEXP = 64, EPVN = 128 };

template <int BN, int MINB, int EPI, typename OutT>
__global__ __launch_bounds__(256, MINB) void k_gemm(
    const u16* __restrict__ A, const u16* __restrict__ B, OutT* __restrict__ C,
    const float* __restrict__ bias, const float* __restrict__ bias2,
    const float* __restrict__ bias3, const float* __restrict__ resid,
    u16* __restrict__ Vt, float* __restrict__ rsum, float scale,
    int N, int K, long sAb, long sBb, long sCb) {
  constexpr int NR = BN / 32;        // B frags per wave per kh (4 or 2)
  constexpr int NBC = BN * 8 / 256;  // B staging chunks per thread (4 or 2)
  __shared__ u16 As[128 * 64];
  __shared__ u16 Bs[BN * 64];
  const int tid = threadIdx.x, lane = tid & 63, wv = tid >> 6;
  const int wr = wv >> 1, wc = wv & 1;
  const int r = lane & 15, q = lane >> 4;

  // XCD-aware supertiled swizzle (requires gridDim.x%8==0 && gridDim.y%8==0)
  const int f = blockIdx.y * gridDim.x + blockIdx.x;
  const int nxy = gridDim.x * gridDim.y;
  const int o = (f & 7) * (nxy >> 3) + (f >> 3);
  const int st = o >> 6, t6 = o & 63;
  const int sxw = gridDim.x >> 3;
  const int bx = (st % sxw) * 8 + (t6 & 7);
  const int by = (st / sxw) * 8 + (t6 >> 3);

  const long bm = (long)by * 128, bn = (long)bx * BN;
  const u16* Ab = A + (long)blockIdx.z * sAb + bm * K;
  const u16* Bb = B + (long)blockIdx.z * sBb + bn * K;

  f32x4 acc[4][NR] = {};

  for (int k0 = 0; k0 < K; k0 += 64) {
#pragma unroll
    for (int i = 0; i < 4; ++i) {
      const int c = i * 256 + tid;
      const int row = c >> 3, sp = c & 7;
      const long g = (long)row * K + k0 + ((sp ^ (row & 7)) << 3);
      gl2lds16(Ab + g, As + c * 8);
    }
#pragma unroll
    for (int i = 0; i < NBC; ++i) {
      const int c = i * 256 + tid;
      const int row = c >> 3, sp = c & 7;
      const long g = (long)row * K + k0 + ((sp ^ (row & 7)) << 3);
      gl2lds16(Bb + g, Bs + c * 8);
    }
    __syncthreads();
    bf16x8 a[8], b[2 * NR];
#pragma unroll
    for (int kh = 0; kh < 2; ++kh) {
#pragma unroll
      for (int i = 0; i < 4; ++i) {
        const int ar = wr * 64 + i * 16 + r;
        a[kh * 4 + i] = *(const bf16x8*)&As[ar * 64 + ((kh * 4 + q) ^ (ar & 7)) * 8];
      }
#pragma unroll
      for (int ni = 0; ni < NR; ++ni) {
        const int br = wc * (BN / 2) + ni * 16 + r;
        b[kh * NR + ni] = *(const bf16x8*)&Bs[br * 64 + ((kh * 4 + q) ^ (br & 7)) * 8];
      }
    }
#pragma unroll
    for (int kh = 0; kh < 2; ++kh)
#pragma unroll
      for (int mi = 0; mi < 4; ++mi)
#pragma unroll
        for (int ni = 0; ni < NR; ++ni)
          acc[mi][ni] = MFMA(a[kh * 4 + mi], b[kh * NR + ni], acc[mi][ni]);
    __syncthreads();
  }

  // ---------------- epilogue (LDS-bounce, vectorized stores) ----------------
  const long cb = (long)blockIdx.z * sCb;
  constexpr bool VMODE = ((EPI & EQKV) != 0);
  const bool isV = VMODE && (bx >= 16);  // QKV: blocks 16..23 are V columns
  float rs[4][4];
  if constexpr ((EPI & EEXP) != 0) {
#pragma unroll
    for (int mi = 0; mi < 4; ++mi)
#pragma unroll
      for (int j = 0; j < 4; ++j) rs[mi][j] = 0.0f;
  }
  float* lb = (float*)As;  // [128][32] f32 = 16 KB bounce buffer

#pragma unroll
  for (int ni = 0; ni < NR; ++ni) {
    const long col = bn + wc * (BN / 2) + ni * 16 + r;
    float bv = 0.0f;
    if constexpr ((EPI & EB) != 0) bv = bias[col];
    if constexpr (VMODE) {
      const int c = (int)col & 1023;
      bv = (bx < 8) ? bias[c] : (bx < 16) ? bias2[c] : bias3[c];
    }
    // compute final values (except residual) into lb / direct Vt store
    ushort4 vo[4];
#pragma unroll
    for (int mi = 0; mi < 4; ++mi) {
      float vj[4];
#pragma unroll
      for (int j = 0; j < 4; ++j) {
        float v = acc[mi][ni][j];
        if constexpr ((EPI & ES) != 0) v *= scale;
        if constexpr ((EPI & EEXP) != 0) {
          v = __expf(v * scale);
          rs[mi][j] += v;
        }
        if constexpr ((EPI & EPVN) != 0) {
          const long row = bm + wr * 64 + mi * 16 + q * 4 + j;
          v *= bias[(long)blockIdx.z * 2048 + row];
        }
        v += bv;
        if constexpr ((EPI & EG) != 0) v = gelu_f(v);
        vj[j] = v;
      }
      if constexpr (VMODE) {
        vo[mi].x = f2b(vj[0]); vo[mi].y = f2b(vj[1]);
        vo[mi].z = f2b(vj[2]); vo[mi].w = f2b(vj[3]);
      }
      if (!isV) {
#pragma unroll
        for (int j = 0; j < 4; ++j)
          lb[(wr * 64 + mi * 16 + q * 4 + j) * 32 + wc * 16 + r] = vj[j];
      }
    }
    if constexpr (VMODE) {
      if (isV) {
        const int c = (int)col & 1023;
#pragma unroll
        for (int mi = 0; mi < 4; ++mi) {
          const long row = bm + wr * 64 + mi * 16 + q * 4;  // 4 consecutive rows
          *(ushort4*)&Vt[((row >> 11) << 21) + ((long)c << 11) + (row & 2047)] = vo[mi];
        }
      }
    }
    __syncthreads();
    if (!isV) {
      // readout: 512 8-col chunks, 2 per thread; 16B/32B vectorized stores
#pragma unroll
      for (int s = 0; s < 2; ++s) {
        const int ch = s * 256 + tid;
        const int row128 = ch >> 2, cc = ch & 3;
        const long grow = bm + row128;
        const long gcol = bn + (long)(cc >> 1) * (BN / 2) + ni * 16 + (cc & 1) * 8;
        float v8[8];
#pragma unroll
        for (int k = 0; k < 8; ++k) v8[k] = lb[row128 * 32 + cc * 8 + k];
        if constexpr ((EPI & ER) != 0) {
          const float4 r0 = *(const float4*)&resid[grow * N + gcol];
          const float4 r1 = *(const float4*)&resid[grow * N + gcol + 4];
          v8[0] += r0.x; v8[1] += r0.y; v8[2] += r0.z; v8[3] += r0.w;
          v8[4] += r1.x; v8[5] += r1.y; v8[6] += r1.z; v8[7] += r1.w;
        }
        if constexpr ((EPI & ERB) != 0) {
          const ushort4 r0 = *(const ushort4*)&((const u16*)resid)[grow * N + gcol];
          const ushort4 r1 = *(const ushort4*)&((const u16*)resid)[grow * N + gcol + 4];
          v8[0] += b2f(r0.x); v8[1] += b2f(r0.y); v8[2] += b2f(r0.z); v8[3] += b2f(r0.w);
          v8[4] += b2f(r1.x); v8[5] += b2f(r1.y); v8[6] += b2f(r1.z); v8[7] += b2f(r1.w);
        }
        if constexpr (VMODE) {
          // Q (bx<8) or K (bx in 8..15): dest selected per block
          u16* dst = (u16*)C + ((bx < 8) ? 0L : 8388608L);
          uint4 o4;
          o4.x = (u32)f2b(v8[0]) | ((u32)f2b(v8[1]) << 16);
          o4.y = (u32)f2b(v8[2]) | ((u32)f2b(v8[3]) << 16);
          o4.z = (u32)f2b(v8[4]) | ((u32)f2b(v8[5]) << 16);
          o4.w = (u32)f2b(v8[6]) | ((u32)f2b(v8[7]) << 16);
          *(uint4*)&dst[grow * 1024 + (gcol & 1023)] = o4;
        } else if constexpr (sizeof(OutT) == 4) {
          float4 f0 = {v8[0], v8[1], v8[2], v8[3]};
          float4 f1 = {v8[4], v8[5], v8[6], v8[7]};
          *(float4*)&C[cb + grow * N + gcol] = f0;
          *(float4*)&C[cb + grow * N + gcol + 4] = f1;
        } else {
          uint4 o4;
          o4.x = (u32)f2b(v8[0]) | ((u32)f2b(v8[1]) << 16);
          o4.y = (u32)f2b(v8[2]) | ((u32)f2b(v8[3]) << 16);
          o4.z = (u32)f2b(v8[4]) | ((u32)f2b(v8[5]) << 16);
          o4.w = (u32)f2b(v8[6]) | ((u32)f2b(v8[7]) << 16);
          *(uint4*)&((u16*)C)[cb + grow * N + gcol] = o4;
        }
      }
    }
    __syncthreads();
  }

  if constexpr ((EPI & EEXP) != 0) {
    // reduce rs over the 16 col-lanes; combine the 2 col-waves via LDS;
    // write per-row partial sums for this block's 128 rows.
    float* rbuf = (float*)As;
#pragma unroll
    for (int mi = 0; mi < 4; ++mi)
#pragma unroll
      for (int j = 0; j < 4; ++j) {
        float v = rs[mi][j];
        v += __shfl_xor(v, 1);
        v += __shfl_xor(v, 2);
        v += __shfl_xor(v, 4);
        v += __shfl_xor(v, 8);
        rs[mi][j] = v;
      }
    __syncthreads();
    if (r == 0) {
#pragma unroll
      for (int mi = 0; mi < 4; ++mi)
#pragma unroll
        for (int j = 0; j < 4; ++j)
          rbuf[wc * 128 + wr * 64 + mi * 16 + q * 4 + j] = rs[mi][j];
    }
    __syncthreads();
    if (tid < 128) {
      const float s = rbuf[tid] + rbuf[128 + tid];
      rsum[(long)bx * 8192 + (long)blockIdx.z * 2048 + bm + tid] = s;
    }
  }
  (void)Vt; (void)rsum; (void)bias2; (void)bias3; (void)resid;
}

extern "C" void kernel_launch(void* const* d_in, const int* in_sizes, int n_in,
                              void* d_out, int out_size, void* d_ws, size_t ws_size,
                              hipStream_t stream) {
  const float* x    = (const float*)d_in[0];
  const float* cond = (const float*)d_in[1];
  const float* n1w  = (const float*)d_in[2];
  const float* f1w  = (const float*)d_in[3];
  const float* f1b  = (const float*)d_in[4];
  const float* qw   = (const float*)d_in[5];
  const float* qb   = (const float*)d_in[6];
  const float* kw   = (const float*)d_in[7];
  const float* kb   = (const float*)d_in[8];
  const float* vw   = (const float*)d_in[9];
  const float* vb   = (const float*)d_in[10];
  const float* pw   = (const float*)d_in[11];
  const float* pb   = (const float*)d_in[12];
  const float* n2w  = (const float*)d_in[13];
  const float* f2w  = (const float*)d_in[14];
  const float* f2b_ = (const float*)d_in[15];
  const float* w1   = (const float*)d_in[16];
  const float* b1   = (const float*)d_in[17];
  const float* w2   = (const float*)d_in[18];
  const float* b2   = (const float*)d_in[19];
  float* out = (float*)d_out;

  char* ws = (char*)d_ws;
  size_t o = 0;
  auto alloc = [&](size_t bytes) {
    size_t ret = o;
    o += (bytes + 255) & ~(size_t)255;
    return ret;
  };
  const long N = 2048, D = 1024, H = 4096;

  u16* qkvT = (u16*)(ws + alloc(3 * D * D * 2));  // [3072][1024] = qT;kT;vT
  u16* pT   = (u16*)(ws + alloc(D * D * 2));
  u16* w1T  = (u16*)(ws + alloc(D * H * 2));
  u16* w2T  = (u16*)(ws + alloc(D * H * 2));
  float* ss    = (float*)(ws + alloc(2 * 4 * 2 * D * 4));   // [2][4][2048]
  float* part  = (float*)(ws + alloc(16 * 4 * 2 * D * 4));  // [16][4][2048]
  float* spart = (float*)(ws + alloc(16 * 8192 * 4));       // S row partials
  float* rsinv = (float*)(ws + alloc(8192 * 4));            // 1/rowsum
  u16* h    = (u16*)(ws + alloc(4 * N * D * 2));    // 16 MB
  u16* x1b  = (u16*)(ws + alloc(4 * N * D * 2));    // 16 MB (bf16 residual)
  u16* AO   = (u16*)(ws + alloc(4 * N * D * 2));    // 16 MB
  const size_t big = o;  // alias region
  u16* Q    = (u16*)(ws + alloc(4 * N * D * 2));    // Q and Kb must stay adjacent
  u16* Kb   = (u16*)(ws + alloc(4 * N * D * 2));
  u16* Vt   = (u16*)(ws + alloc(4 * N * D * 2));
  u16* S    = (u16*)(ws + alloc(4 * N * N * 2));    // 32 MB
  u16* h1   = (u16*)(ws + big);                     // 64 MB, aliases Q..S
  (void)ws_size; (void)in_sizes; (void)n_in; (void)out_size; (void)Kb;

  // fused weight transposes (q,k,v,p,w1,w2)
  T6 td;
  td.d[0] = {qw, qkvT,                1024, 1024,    0,  32};
  td.d[1] = {kw, qkvT + 1024 * 1024,  1024, 1024, 1024,  32};
  td.d[2] = {vw, qkvT + 2048 * 1024,  1024, 1024, 2048,  32};
  td.d[3] = {pw, pT,                  1024, 1024, 3072,  32};
  td.d[4] = {w1, w1T,                 1024, 4096, 4096, 128};
  td.d[5] = {w2, w2T,                 4096, 1024, 8192,  32};
  k_transpose6<<<12288, dim3(32, 8), 0, stream>>>(td);

  k_film_part<<<dim3(8, 4, 16), 256, 0, stream>>>(cond, f1w, f2w, part);
  k_film_comb<<<dim3(8, 8), 256, 0, stream>>>(part, f1b, f2b_, ss);

  k_rmsfilm<float><<<8192, 256, 0, stream>>>(x, n1w, ss, h);

  // fused QKV: [8192,1024] @ [3072,1024]^T ; V stored transposed per batch
  k_gemm<128, 5, EQKV, u16><<<dim3(24, 64, 1), 256, 0, stream>>>(
      h, qkvT, Q, qb, kb, vb, nullptr, Vt, nullptr, 1.0f, 3072, 1024, 0, 0, 0);

  // S = exp(Q @ K^T * D^-0.5), unnormalized; per-block row partial sums
  k_gemm<128, 5, EEXP, u16><<<dim3(16, 16, 4), 256, 0, stream>>>(
      Q, Kb, S, nullptr, nullptr, nullptr, nullptr, nullptr, spart, 0.03125f,
      2048, 1024, N * D, N * D, N * N);
  k_rowsuminv<<<32, 256, 0, stream>>>(spart, rsinv);

  // AO = (P @ V) * inv_rowsum (batched; B-operand = Vt[d][n]; BN=64 -> 1024 blocks)
  k_gemm<64, 6, EPVN, u16><<<dim3(16, 16, 4), 256, 0, stream>>>(
      S, Vt, AO, rsinv, nullptr, nullptr, nullptr, nullptr, nullptr, 1.0f,
      1024, 2048, N * N, D * N, N * D);

  // x1 = x + AO @ proj^T + pb   (stored bf16; BN=64 -> 1024 blocks)
  k_gemm<64, 6, EB | ER, u16><<<dim3(16, 64, 1), 256, 0, stream>>>(
      AO, pT, x1b, pb, nullptr, nullptr, x, nullptr, nullptr, 1.0f, 1024, 1024, 0, 0, 0);

  k_rmsfilm<u16><<<8192, 256, 0, stream>>>(x1b, n2w, ss + 4 * 2048, h);

  // h1 = gelu(h @ w1 + b1)
  k_gemm<128, 5, EB | EG, u16><<<dim3(32, 64, 1), 256, 0, stream>>>(
      h, w1T, h1, b1, nullptr, nullptr, nullptr, nullptr, nullptr, 1.0f, 4096, 1024, 0, 0, 0);

  // out = x1 + h1 @ w2 + b2   (BN=64 -> 1024 blocks)
  k_gemm<64, 6, EB | ERB, float><<<dim3(16, 64, 1), 256, 0, stream>>>(
      h1, w2T, out, b2, nullptr, nullptr, (const float*)x1b, nullptr, nullptr, 1.0f,
      1024, 4096, 0, 0, 0);
}

// Round 15
// 378.508 us; speedup vs baseline: 1.3529x; 1.3529x over previous
//
#include <hip/hip_runtime.h>
#include <math.h>

typedef unsigned short u16;
typedef unsigned int u32;
typedef __bf16 bf16;
typedef bf16 bf16x8 __attribute__((ext_vector_type(8)));
typedef float f32x4 __attribute__((ext_vector_type(4)));

#define DEV __device__ __forceinline__
#define MFMA(a, b, c) __builtin_amdgcn_mfma_f32_16x16x32_bf16(a, b, c, 0, 0, 0)

DEV u16 f2b(float f) {
  unsigned u = __builtin_bit_cast(unsigned, f);
  u += 0x7fffu + ((u >> 16) & 1u);
  return (u16)(u >> 16);
}
DEV float b2f(u16 h) {
  unsigned u = ((unsigned)h) << 16;
  return __builtin_bit_cast(float, u);
}
// gelu(x) ~= x * sigmoid(1.5957691x + 0.0713548x^3)  (tanh-form, |err|<=0.003)
DEV float gelu_f(float x) {
  float e = __expf(x * (-1.5957691216f - 0.07135481283f * x * x));
  return x / (1.0f + e);
}

DEV void gl2lds16(const void* g, void* l) {
  __builtin_amdgcn_global_load_lds(
      (const __attribute__((address_space(1))) unsigned int*)g,
      (__attribute__((address_space(3))) unsigned int*)l, 16, 0, 0);
}

// ---------------- fused 6-matrix transpose + fp32->bf16 ----------------
struct TDesc { const float* src; u16* dst; int R, C, t0, tx; };
struct T6 { TDesc d[6]; };

__global__ void k_transpose6(T6 td) {
  __shared__ float tile[32][33];
  const int id = blockIdx.x;
  TDesc d = td.d[0];
#pragma unroll
  for (int k = 1; k < 6; ++k)
    if (id >= td.d[k].t0) d = td.d[k];
  const int local = id - d.t0;
  const int c0 = (local % d.tx) * 32, r0 = (local / d.tx) * 32;
  const int tx = threadIdx.x, ty = threadIdx.y;  // 32 x 8
#pragma unroll
  for (int i = 0; i < 32; i += 8)
    tile[ty + i][tx] = d.src[(long)(r0 + ty + i) * d.C + c0 + tx];
  __syncthreads();
#pragma unroll
  for (int i = 0; i < 32; i += 8)
    d.dst[(long)(c0 + ty + i) * d.R + r0 + tx] = f2b(tile[tx][ty + i]);
}

// ---------------- FiLM ss = cond @ fw + fb, split-K, both films ----------------
__global__ __launch_bounds__(256) void k_film_part(const float* __restrict__ cond,
                                                   const float* __restrict__ f1w,
                                                   const float* __restrict__ f2w,
                                                   float* __restrict__ part) {
  const int j = blockIdx.x * 256 + threadIdx.x;  // 0..2047
  const int b = blockIdx.y;                      // 0..3
  const int z = blockIdx.z;                      // 0..15
  const int kz = z & 7;
  const float* fw = (z < 8) ? f1w : f2w;
  const float* cp = cond + b * 1024 + kz * 128;
  const float* wp = fw + (long)kz * 128 * 2048 + j;
  float acc = 0.0f;
#pragma unroll 4
  for (int d = 0; d < 128; ++d) acc = fmaf(cp[d], wp[(long)d * 2048], acc);
  part[((z * 4 + b) << 11) + j] = acc;
}
__global__ __launch_bounds__(256) void k_film_comb(const float* __restrict__ part,
                                                   const float* __restrict__ f1b,
                                                   const float* __restrict__ f2b_,
                                                   float* __restrict__ ss) {
  const int j = blockIdx.x * 256 + threadIdx.x;
  const int b = blockIdx.y & 3, f = blockIdx.y >> 2;
  float a = (f ? f2b_ : f1b)[j];
#pragma unroll
  for (int kz = 0; kz < 8; ++kz) a += part[(((f * 8 + kz) * 4 + b) << 11) + j];
  ss[((f * 4 + b) << 11) + j] = a;
}

// ---------------- fused RMSNorm + FiLM -> bf16 (fp32 or bf16 input) ----------------
template <typename InT>
__global__ __launch_bounds__(256) void k_rmsfilm(const InT* __restrict__ x,
                                                 const float* __restrict__ nw,
                                                 const float* __restrict__ ss,
                                                 u16* __restrict__ h) {
  const int row = blockIdx.x;
  const int b = row >> 11;
  const int t = threadIdx.x;
  float4 v;
  if constexpr (sizeof(InT) == 4) {
    v = ((const float4*)(x + (long)row * 1024))[t];
  } else {
    ushort4 u = ((const ushort4*)(x + (long)row * 1024))[t];
    v = make_float4(b2f(u.x), b2f(u.y), b2f(u.z), b2f(u.w));
  }
  float s = v.x * v.x + v.y * v.y + v.z * v.z + v.w * v.w;
#pragma unroll
  for (int off = 32; off; off >>= 1) s += __shfl_xor(s, off);
  __shared__ float red[4];
  const int wv = t >> 6, lane = t & 63;
  if (lane == 0) red[wv] = s;
  __syncthreads();
  const float tot = red[0] + red[1] + red[2] + red[3];
  const float rn = rsqrtf(tot * (1.0f / 1024.0f) + 1e-6f);
  const float4 w4 = ((const float4*)nw)[t];
  const float4 sc = ((const float4*)(ss + b * 2048))[t];
  const float4 sh = ((const float4*)(ss + b * 2048 + 1024))[t];
  ushort4 o;
  o.x = f2b(v.x * rn * w4.x * (1.0f + sc.x) + sh.x);
  o.y = f2b(v.y * rn * w4.y * (1.0f + sc.y) + sh.y);
  o.z = f2b(v.z * rn * w4.z * (1.0f + sc.z) + sh.z);
  o.w = f2b(v.w * rn * w4.w * (1.0f + sc.w) + sh.w);
  ((ushort4*)(h + (long)row * 1024))[t] = o;
}

// ---------------- rowsum combine: inv[r] = 1 / sum_b part[b][r] ----------------
__global__ __launch_bounds__(256) void k_rowsuminv(const float* __restrict__ part,
                                                   float* __restrict__ inv) {
  const int id = blockIdx.x * 256 + threadIdx.x;  // 0..8191
  float s = 0.0f;
#pragma unroll
  for (int b = 0; b < 16; ++b) s += part[b * 8192 + id];
  inv[id] = 1.0f / s;
}

// ---------------- m97-form bf16 MFMA GEMM, 128xBN tile, BK=64 ----------------
// C = A[M,K] @ Bt[N,K]^T. 4 waves (2x2), single-buffered LDS, 2 syncs per
// K-step. LDS rows 128B (BK=64); XOR-swizzle slot^=(row&7) on the pre-swizzled
// global source (linear global_load_lds dest) and on ds_read.
// Block mapping: 8x8 supertile traversal per XCD (4MB L2 window).
// Epilogue: LDS-bounce -> 16B vectorized stores; V-columns direct to Vt.
// NOTE: __launch_bounds__(256,4) — R14 showed 5/6 squeezes VGPR to 48 and
// costs 33% on the K-loop; 4 keeps VGPR=64 (validated best).
enum { EB = 1, ES = 2, EG = 4, ER = 8, EQKV = 16, ERB = 32, EEXP = 64, EPVN = 128 };

template <int BN, int EPI, typename OutT>
__global__ __launch_bounds__(256, 4) void k_gemm(
    const u16* __restrict__ A, const u16* __restrict__ B, OutT* __restrict__ C,
    const float* __restrict__ bias, const float* __restrict__ bias2,
    const float* __restrict__ bias3, const float* __restrict__ resid,
    u16* __restrict__ Vt, float* __restrict__ rsum, float scale,
    int N, int K, long sAb, long sBb, long sCb) {
  constexpr int NR = BN / 32;        // B frags per wave per kh (4 or 2)
  constexpr int NBC = BN * 8 / 256;  // B staging chunks per thread (4 or 2)
  __shared__ u16 As[128 * 64];
  __shared__ u16 Bs[BN * 64];
  const int tid = threadIdx.x, lane = tid & 63, wv = tid >> 6;
  const int wr = wv >> 1, wc = wv & 1;
  const int r = lane & 15, q = lane >> 4;

  // XCD-aware supertiled swizzle (requires gridDim.x%8==0 && gridDim.y%8==0)
  const int f = blockIdx.y * gridDim.x + blockIdx.x;
  const int nxy = gridDim.x * gridDim.y;
  const int o = (f & 7) * (nxy >> 3) + (f >> 3);
  const int st = o >> 6, t6 = o & 63;
  const int sxw = gridDim.x >> 3;
  const int bx = (st % sxw) * 8 + (t6 & 7);
  const int by = (st / sxw) * 8 + (t6 >> 3);

  const long bm = (long)by * 128, bn = (long)bx * BN;
  const u16* Ab = A + (long)blockIdx.z * sAb + bm * K;
  const u16* Bb = B + (long)blockIdx.z * sBb + bn * K;

  f32x4 acc[4][NR] = {};

  for (int k0 = 0; k0 < K; k0 += 64) {
#pragma unroll
    for (int i = 0; i < 4; ++i) {
      const int c = i * 256 + tid;
      const int row = c >> 3, sp = c & 7;
      const long g = (long)row * K + k0 + ((sp ^ (row & 7)) << 3);
      gl2lds16(Ab + g, As + c * 8);
    }
#pragma unroll
    for (int i = 0; i < NBC; ++i) {
      const int c = i * 256 + tid;
      const int row = c >> 3, sp = c & 7;
      const long g = (long)row * K + k0 + ((sp ^ (row & 7)) << 3);
      gl2lds16(Bb + g, Bs + c * 8);
    }
    __syncthreads();
    bf16x8 a[8], b[2 * NR];
#pragma unroll
    for (int kh = 0; kh < 2; ++kh) {
#pragma unroll
      for (int i = 0; i < 4; ++i) {
        const int ar = wr * 64 + i * 16 + r;
        a[kh * 4 + i] = *(const bf16x8*)&As[ar * 64 + ((kh * 4 + q) ^ (ar & 7)) * 8];
      }
#pragma unroll
      for (int ni = 0; ni < NR; ++ni) {
        const int br = wc * (BN / 2) + ni * 16 + r;
        b[kh * NR + ni] = *(const bf16x8*)&Bs[br * 64 + ((kh * 4 + q) ^ (br & 7)) * 8];
      }
    }
#pragma unroll
    for (int kh = 0; kh < 2; ++kh)
#pragma unroll
      for (int mi = 0; mi < 4; ++mi)
#pragma unroll
        for (int ni = 0; ni < NR; ++ni)
          acc[mi][ni] = MFMA(a[kh * 4 + mi], b[kh * NR + ni], acc[mi][ni]);
    __syncthreads();
  }

  // ---------------- epilogue (LDS-bounce, vectorized stores) ----------------
  const long cb = (long)blockIdx.z * sCb;
  constexpr bool VMODE = ((EPI & EQKV) != 0);
  const bool isV = VMODE && (bx >= 16);  // QKV: blocks 16..23 are V columns
  float rs[4][4];
  if constexpr ((EPI & EEXP) != 0) {
#pragma unroll
    for (int mi = 0; mi < 4; ++mi)
#pragma unroll
      for (int j = 0; j < 4; ++j) rs[mi][j] = 0.0f;
  }
  float* lb = (float*)As;  // [128][32] f32 = 16 KB bounce buffer

#pragma unroll
  for (int ni = 0; ni < NR; ++ni) {
    const long col = bn + wc * (BN / 2) + ni * 16 + r;
    float bv = 0.0f;
    if constexpr ((EPI & EB) != 0) bv = bias[col];
    if constexpr (VMODE) {
      const int c = (int)col & 1023;
      bv = (bx < 8) ? bias[c] : (bx < 16) ? bias2[c] : bias3[c];
    }
    // compute final values (except residual) into lb / direct Vt store
    ushort4 vo[4];
#pragma unroll
    for (int mi = 0; mi < 4; ++mi) {
      float vj[4];
#pragma unroll
      for (int j = 0; j < 4; ++j) {
        float v = acc[mi][ni][j];
        if constexpr ((EPI & ES) != 0) v *= scale;
        if constexpr ((EPI & EEXP) != 0) {
          v = __expf(v * scale);
          rs[mi][j] += v;
        }
        if constexpr ((EPI & EPVN) != 0) {
          const long row = bm + wr * 64 + mi * 16 + q * 4 + j;
          v *= bias[(long)blockIdx.z * 2048 + row];
        }
        v += bv;
        if constexpr ((EPI & EG) != 0) v = gelu_f(v);
        vj[j] = v;
      }
      if constexpr (VMODE) {
        vo[mi].x = f2b(vj[0]); vo[mi].y = f2b(vj[1]);
        vo[mi].z = f2b(vj[2]); vo[mi].w = f2b(vj[3]);
      }
      if (!isV) {
#pragma unroll
        for (int j = 0; j < 4; ++j)
          lb[(wr * 64 + mi * 16 + q * 4 + j) * 32 + wc * 16 + r] = vj[j];
      }
    }
    if constexpr (VMODE) {
      if (isV) {
        const int c = (int)col & 1023;
#pragma unroll
        for (int mi = 0; mi < 4; ++mi) {
          const long row = bm + wr * 64 + mi * 16 + q * 4;  // 4 consecutive rows
          *(ushort4*)&Vt[((row >> 11) << 21) + ((long)c << 11) + (row & 2047)] = vo[mi];
        }
      }
    }
    __syncthreads();
    if (!isV) {
      // readout: 512 8-col chunks, 2 per thread; 16B/32B vectorized stores
#pragma unroll
      for (int s = 0; s < 2; ++s) {
        const int ch = s * 256 + tid;
        const int row128 = ch >> 2, cc = ch & 3;
        const long grow = bm + row128;
        const long gcol = bn + (long)(cc >> 1) * (BN / 2) + ni * 16 + (cc & 1) * 8;
        float v8[8];
#pragma unroll
        for (int k = 0; k < 8; ++k) v8[k] = lb[row128 * 32 + cc * 8 + k];
        if constexpr ((EPI & ER) != 0) {
          const float4 r0 = *(const float4*)&resid[grow * N + gcol];
          const float4 r1 = *(const float4*)&resid[grow * N + gcol + 4];
          v8[0] += r0.x; v8[1] += r0.y; v8[2] += r0.z; v8[3] += r0.w;
          v8[4] += r1.x; v8[5] += r1.y; v8[6] += r1.z; v8[7] += r1.w;
        }
        if constexpr ((EPI & ERB) != 0) {
          const ushort4 r0 = *(const ushort4*)&((const u16*)resid)[grow * N + gcol];
          const ushort4 r1 = *(const ushort4*)&((const u16*)resid)[grow * N + gcol + 4];
          v8[0] += b2f(r0.x); v8[1] += b2f(r0.y); v8[2] += b2f(r0.z); v8[3] += b2f(r0.w);
          v8[4] += b2f(r1.x); v8[5] += b2f(r1.y); v8[6] += b2f(r1.z); v8[7] += b2f(r1.w);
        }
        if constexpr (VMODE) {
          // Q (bx<8) or K (bx in 8..15): dest selected per block
          u16* dst = (u16*)C + ((bx < 8) ? 0L : 8388608L);
          uint4 o4;
          o4.x = (u32)f2b(v8[0]) | ((u32)f2b(v8[1]) << 16);
          o4.y = (u32)f2b(v8[2]) | ((u32)f2b(v8[3]) << 16);
          o4.z = (u32)f2b(v8[4]) | ((u32)f2b(v8[5]) << 16);
          o4.w = (u32)f2b(v8[6]) | ((u32)f2b(v8[7]) << 16);
          *(uint4*)&dst[grow * 1024 + (gcol & 1023)] = o4;
        } else if constexpr (sizeof(OutT) == 4) {
          float4 f0 = {v8[0], v8[1], v8[2], v8[3]};
          float4 f1 = {v8[4], v8[5], v8[6], v8[7]};
          *(float4*)&C[cb + grow * N + gcol] = f0;
          *(float4*)&C[cb + grow * N + gcol + 4] = f1;
        } else {
          uint4 o4;
          o4.x = (u32)f2b(v8[0]) | ((u32)f2b(v8[1]) << 16);
          o4.y = (u32)f2b(v8[2]) | ((u32)f2b(v8[3]) << 16);
          o4.z = (u32)f2b(v8[4]) | ((u32)f2b(v8[5]) << 16);
          o4.w = (u32)f2b(v8[6]) | ((u32)f2b(v8[7]) << 16);
          *(uint4*)&((u16*)C)[cb + grow * N + gcol] = o4;
        }
      }
    }
    __syncthreads();
  }

  if constexpr ((EPI & EEXP) != 0) {
    // reduce rs over the 16 col-lanes; combine the 2 col-waves via LDS;
    // write per-row partial sums for this block's 128 rows.
    float* rbuf = (float*)As;
#pragma unroll
    for (int mi = 0; mi < 4; ++mi)
#pragma unroll
      for (int j = 0; j < 4; ++j) {
        float v = rs[mi][j];
        v += __shfl_xor(v, 1);
        v += __shfl_xor(v, 2);
        v += __shfl_xor(v, 4);
        v += __shfl_xor(v, 8);
        rs[mi][j] = v;
      }
    __syncthreads();
    if (r == 0) {
#pragma unroll
      for (int mi = 0; mi < 4; ++mi)
#pragma unroll
        for (int j = 0; j < 4; ++j)
          rbuf[wc * 128 + wr * 64 + mi * 16 + q * 4 + j] = rs[mi][j];
    }
    __syncthreads();
    if (tid < 128) {
      const float s = rbuf[tid] + rbuf[128 + tid];
      rsum[(long)bx * 8192 + (long)blockIdx.z * 2048 + bm + tid] = s;
    }
  }
  (void)Vt; (void)rsum; (void)bias2; (void)bias3; (void)resid;
}

extern "C" void kernel_launch(void* const* d_in, const int* in_sizes, int n_in,
                              void* d_out, int out_size, void* d_ws, size_t ws_size,
                              hipStream_t stream) {
  const float* x    = (const float*)d_in[0];
  const float* cond = (const float*)d_in[1];
  const float* n1w  = (const float*)d_in[2];
  const float* f1w  = (const float*)d_in[3];
  const float* f1b  = (const float*)d_in[4];
  const float* qw   = (const float*)d_in[5];
  const float* qb   = (const float*)d_in[6];
  const float* kw   = (const float*)d_in[7];
  const float* kb   = (const float*)d_in[8];
  const float* vw   = (const float*)d_in[9];
  const float* vb   = (const float*)d_in[10];
  const float* pw   = (const float*)d_in[11];
  const float* pb   = (const float*)d_in[12];
  const float* n2w  = (const float*)d_in[13];
  const float* f2w  = (const float*)d_in[14];
  const float* f2b_ = (const float*)d_in[15];
  const float* w1   = (const float*)d_in[16];
  const float* b1   = (const float*)d_in[17];
  const float* w2   = (const float*)d_in[18];
  const float* b2   = (const float*)d_in[19];
  float* out = (float*)d_out;

  char* ws = (char*)d_ws;
  size_t o = 0;
  auto alloc = [&](size_t bytes) {
    size_t ret = o;
    o += (bytes + 255) & ~(size_t)255;
    return ret;
  };
  const long N = 2048, D = 1024, H = 4096;

  u16* qkvT = (u16*)(ws + alloc(3 * D * D * 2));  // [3072][1024] = qT;kT;vT
  u16* pT   = (u16*)(ws + alloc(D * D * 2));
  u16* w1T  = (u16*)(ws + alloc(D * H * 2));
  u16* w2T  = (u16*)(ws + alloc(D * H * 2));
  float* ss    = (float*)(ws + alloc(2 * 4 * 2 * D * 4));   // [2][4][2048]
  float* part  = (float*)(ws + alloc(16 * 4 * 2 * D * 4));  // [16][4][2048]
  float* spart = (float*)(ws + alloc(16 * 8192 * 4));       // S row partials
  float* rsinv = (float*)(ws + alloc(8192 * 4));            // 1/rowsum
  u16* h    = (u16*)(ws + alloc(4 * N * D * 2));    // 16 MB
  u16* x1b  = (u16*)(ws + alloc(4 * N * D * 2));    // 16 MB (bf16 residual)
  u16* AO   = (u16*)(ws + alloc(4 * N * D * 2));    // 16 MB
  const size_t big = o;  // alias region
  u16* Q    = (u16*)(ws + alloc(4 * N * D * 2));    // Q and Kb must stay adjacent
  u16* Kb   = (u16*)(ws + alloc(4 * N * D * 2));
  u16* Vt   = (u16*)(ws + alloc(4 * N * D * 2));
  u16* S    = (u16*)(ws + alloc(4 * N * N * 2));    // 32 MB
  u16* h1   = (u16*)(ws + big);                     // 64 MB, aliases Q..S
  (void)ws_size; (void)in_sizes; (void)n_in; (void)out_size; (void)Kb;

  // fused weight transposes (q,k,v,p,w1,w2)
  T6 td;
  td.d[0] = {qw, qkvT,                1024, 1024,    0,  32};
  td.d[1] = {kw, qkvT + 1024 * 1024,  1024, 1024, 1024,  32};
  td.d[2] = {vw, qkvT + 2048 * 1024,  1024, 1024, 2048,  32};
  td.d[3] = {pw, pT,                  1024, 1024, 3072,  32};
  td.d[4] = {w1, w1T,                 1024, 4096, 4096, 128};
  td.d[5] = {w2, w2T,                 4096, 1024, 8192,  32};
  k_transpose6<<<12288, dim3(32, 8), 0, stream>>>(td);

  k_film_part<<<dim3(8, 4, 16), 256, 0, stream>>>(cond, f1w, f2w, part);
  k_film_comb<<<dim3(8, 8), 256, 0, stream>>>(part, f1b, f2b_, ss);

  k_rmsfilm<float><<<8192, 256, 0, stream>>>(x, n1w, ss, h);

  // fused QKV: [8192,1024] @ [3072,1024]^T ; V stored transposed per batch
  k_gemm<128, EQKV, u16><<<dim3(24, 64, 1), 256, 0, stream>>>(
      h, qkvT, Q, qb, kb, vb, nullptr, Vt, nullptr, 1.0f, 3072, 1024, 0, 0, 0);

  // S = exp(Q @ K^T * D^-0.5), unnormalized; per-block row partial sums
  k_gemm<128, EEXP, u16><<<dim3(16, 16, 4), 256, 0, stream>>>(
      Q, Kb, S, nullptr, nullptr, nullptr, nullptr, nullptr, spart, 0.03125f,
      2048, 1024, N * D, N * D, N * N);
  k_rowsuminv<<<32, 256, 0, stream>>>(spart, rsinv);

  // AO = (P @ V) * inv_rowsum (batched; B-operand = Vt[d][n]; BN=64 -> 1024 blocks)
  k_gemm<64, EPVN, u16><<<dim3(16, 16, 4), 256, 0, stream>>>(
      S, Vt, AO, rsinv, nullptr, nullptr, nullptr, nullptr, nullptr, 1.0f,
      1024, 2048, N * N, D * N, N * D);

  // x1 = x + AO @ proj^T + pb   (stored bf16; BN=64 -> 1024 blocks)
  k_gemm<64, EB | ER, u16><<<dim3(16, 64, 1), 256, 0, stream>>>(
      AO, pT, x1b, pb, nullptr, nullptr, x, nullptr, nullptr, 1.0f, 1024, 1024, 0, 0, 0);

  k_rmsfilm<u16><<<8192, 256, 0, stream>>>(x1b, n2w, ss + 4 * 2048, h);

  // h1 = gelu(h @ w1 + b1)
  k_gemm<128, EB | EG, u16><<<dim3(32, 64, 1), 256, 0, stream>>>(
      h, w1T, h1, b1, nullptr, nullptr, nullptr, nullptr, nullptr, 1.0f, 4096, 1024, 0, 0, 0);

  // out = x1 + h1 @ w2 + b2   (BN=64 -> 1024 blocks)
  k_gemm<64, EB | ERB, float><<<dim3(16, 64, 1), 256, 0, stream>>>(
      h1, w2T, out, b2, nullptr, nullptr, (const float*)x1b, nullptr, nullptr, 1.0f,
      1024, 4096, 0, 0, 0);
}